// Round 5
// baseline (462.316 us; speedup 1.0000x reference)
//
#include <hip/hip_runtime.h>
#include <hip/hip_bf16.h>
#include <stdint.h>

#define TT 4096   // tokens = B*S
#define HH 1024   // hidden
#define II 2048   // intermediate
#define EE 8      // experts
#define RB 64     // router tokens per block
#define CSTRIDE 32  // cnt padding: one counter per 128-B line

typedef short bf16x8 __attribute__((ext_vector_type(8)));
typedef float f32x4 __attribute__((ext_vector_type(4)));

__device__ __forceinline__ unsigned short f2bf(float f) {
  unsigned u = __float_as_uint(f);
  u += 0x7FFF + ((u >> 16) & 1);   // RNE
  return (unsigned short)(u >> 16);
}

__device__ __forceinline__ void gl_lds16(const void* g, void* l) {
  auto gp = reinterpret_cast<const __attribute__((address_space(1))) unsigned int*>(
      reinterpret_cast<uintptr_t>(g));
  auto lp = reinterpret_cast<__attribute__((address_space(3))) unsigned int*>(
      reinterpret_cast<uintptr_t>(l));
  __builtin_amdgcn_global_load_lds(gp, lp, 16, 0, 0);
}

// ------- prep: fused weight transposes + x cast -------
// z: 0..7 gate^T, 8..15 up^T, 16..23 out_w^T, 24..31 x->bf16 cast.
__global__ void prep_kernel(const float* __restrict__ gw, const float* __restrict__ uw,
                            const float* __restrict__ ow, const float* __restrict__ x,
                            unsigned short* __restrict__ gwt, unsigned short* __restrict__ uwt,
                            unsigned short* __restrict__ owt, unsigned short* __restrict__ xb) {
  __shared__ unsigned int tl[64 * 32];
  int z = blockIdx.z;
  int which = z >> 3, e = z & 7;
  int tid = threadIdx.x;

  if (which == 3) {
    // straight cast: 512 blocks x 4 iters x 256 threads x 8 elems = TT*HH
    size_t b0 = (size_t)blockIdx.x * 8192;
#pragma unroll
    for (int it = 0; it < 4; ++it) {
      size_t i = b0 + it * 2048 + tid * 8;
      float4 a = *(const float4*)(x + i);
      float4 b = *(const float4*)(x + i + 4);
      union { unsigned short s[8]; uint4 v; } o;
      o.s[0] = f2bf(a.x); o.s[1] = f2bf(a.y); o.s[2] = f2bf(a.z); o.s[3] = f2bf(a.w);
      o.s[4] = f2bf(b.x); o.s[5] = f2bf(b.y); o.s[6] = f2bf(b.z); o.s[7] = f2bf(b.w);
      *(uint4*)(xb + i) = o.v;
    }
    return;
  }

  const float* in; unsigned short* out; int M, N;
  if (which == 0)      { in = gw; out = gwt; M = HH; N = II; }
  else if (which == 1) { in = uw; out = uwt; M = HH; N = II; }
  else                 { in = ow; out = owt; M = II; N = HH; }
  int nb = N / 64;
  int bx = blockIdx.x % nb, by = blockIdx.x / nb;
  size_t base = (size_t)e * M * N;
  int mB = by * 64, nB = bx * 64;

  union F4 { float4 v; float f[4]; };
  int c4 = (tid & 15) * 4;   // n base
  int mp = tid >> 4;         // 0..15
#pragma unroll
  for (int it = 0; it < 2; ++it) {
    int m = (mp + it * 16) * 2;
    const float* p0 = in + base + (size_t)(mB + m) * N + nB + c4;
    F4 a, b;
    a.v = *(const float4*)p0;
    b.v = *(const float4*)(p0 + N);
    int mdw = m >> 1;
#pragma unroll
    for (int i = 0; i < 4; ++i) {
      int n = c4 + i;
      unsigned v = (unsigned)f2bf(a.f[i]) | ((unsigned)f2bf(b.f[i]) << 16);
      tl[n * 32 + ((mdw + n) & 31)] = v;
    }
  }
  __syncthreads();
  int n2 = tid >> 3;          // 0..31
  int md8 = (tid & 7) * 4;    // dword base within row
#pragma unroll
  for (int it = 0; it < 2; ++it) {
    int n = n2 + it * 32;
    unsigned vv[4];
#pragma unroll
    for (int i = 0; i < 4; ++i)
      vv[i] = tl[n * 32 + ((md8 + i + n) & 31)];
    uint4 o4 = make_uint4(vv[0], vv[1], vv[2], vv[3]);
    *(uint4*)(out + base + (size_t)(nB + n) * M + mB + md8 * 2) = o4;
  }
}

// ------- router: logits, top-2, expert lists (64 blocks, padded counters) -------
__global__ void router_kernel(const float* __restrict__ x, const float* __restrict__ rw,
                              float* __restrict__ logits_out, int* __restrict__ cnt,
                              int* __restrict__ list, int* __restrict__ tslot,
                              float2* __restrict__ tw) {
  __shared__ int bcnt[EE];
  __shared__ int bbase[EE];
  __shared__ int te[RB][2];
  int tid = threadIdx.x, wave = tid >> 6, lane = tid & 63;
  if (tid < EE) bcnt[tid] = 0;
  __syncthreads();
  int t0 = blockIdx.x * RB;

  for (int sub = 0; sub < RB / 4; ++sub) {
    int li = sub * 4 + wave;
    int t = t0 + li;
    float acc[EE];
#pragma unroll
    for (int e = 0; e < EE; ++e) acc[e] = 0.f;
#pragma unroll
    for (int j = 0; j < 4; ++j) {
      int h = j * 256 + lane * 4;
      union F4 { float4 v; float f[4]; } xv;
      xv.v = *(const float4*)(x + (size_t)t * HH + h);
#pragma unroll
      for (int i = 0; i < 4; ++i) {
        const float4* r4 = (const float4*)(rw + (h + i) * EE);
        float4 r0 = r4[0], r1 = r4[1];
        float xs = xv.f[i];
        acc[0] += xs * r0.x; acc[1] += xs * r0.y; acc[2] += xs * r0.z; acc[3] += xs * r0.w;
        acc[4] += xs * r1.x; acc[5] += xs * r1.y; acc[6] += xs * r1.z; acc[7] += xs * r1.w;
      }
    }
#pragma unroll
    for (int e = 0; e < EE; ++e)
#pragma unroll
      for (int off = 32; off; off >>= 1) acc[e] += __shfl_down(acc[e], off);
    if (lane == 0) {
      float4* lo = (float4*)(logits_out + (size_t)t * EE);
      lo[0] = make_float4(acc[0], acc[1], acc[2], acc[3]);
      lo[1] = make_float4(acc[4], acc[5], acc[6], acc[7]);
      int e0 = 0; float b0 = acc[0];
#pragma unroll
      for (int e = 1; e < EE; ++e) if (acc[e] > b0) { b0 = acc[e]; e0 = e; }
      int e1 = -1; float b1 = -3.4e38f;
#pragma unroll
      for (int e = 0; e < EE; ++e) if (e != e0 && acc[e] > b1) { b1 = acc[e]; e1 = e; }
      float w0 = 1.f / (1.f + __expf(b1 - b0));
      tw[t] = make_float2(w0, 1.f - w0);
      int lp0 = atomicAdd(&bcnt[e0], 1);
      int lp1 = atomicAdd(&bcnt[e1], 1);
      te[li][0] = e0 | (lp0 << 8);
      te[li][1] = e1 | (lp1 << 8);
    }
  }
  __syncthreads();
  if (tid < EE) bbase[tid] = atomicAdd(&cnt[tid * CSTRIDE], bcnt[tid]);
  __syncthreads();
  if (tid < RB * 2) {
    int li = tid >> 1, s = tid & 1;
    int v = te[li][s];
    int e = v & 255, lp = v >> 8;
    int p = bbase[e] + lp;
    int t = t0 + li;
    list[e * TT + p] = t;
    tslot[t * 2 + s] = (e << 16) | p;
  }
}

// ---------------- GEMM1: gathered x @ (gate_w,up_w) -> silu(g)*u, bf16 ----------------
// 128(M) x 64(N) x2 tensors, BK=64; LDS: A 1024 chunks, Bg 512, Bu 512 (32KB)
__launch_bounds__(256, 3)
__global__ void gemm1_kernel(const unsigned short* __restrict__ xb,
                             const unsigned short* __restrict__ gwt,
                             const unsigned short* __restrict__ uwt,
                             unsigned short* __restrict__ hidden,
                             const int* __restrict__ cnt, const int* __restrict__ list) {
  int e = blockIdx.z;
  int cn = cnt[e * CSTRIDE];
  int hb0 = 0;
  for (int i = 0; i < EE; ++i) hb0 += (i < e) ? cnt[i * CSTRIDE] : 0;
  int mBase = blockIdx.y * 128;
  if (mBase >= cn) return;
  int nBase = blockIdx.x * 64;

  __shared__ __align__(16) unsigned short smem[16384];  // 2048 x 16B chunks
  __shared__ int stok[128];

  int tid = threadIdx.x, wave = tid >> 6, lane = tid & 63;
  if (tid < 128) {
    int g = mBase + tid;
    stok[tid] = list[e * TT + (g < cn ? g : cn - 1)];
  }
  __syncthreads();

  const char* gaddr[8];
#pragma unroll
  for (int j = 0; j < 8; ++j) {
    int c = wave * 512 + j * 64 + lane;
    const char* g;
    if (c < 1024) {
      int r = c >> 3, sl = (c & 7) ^ (r & 7);
      g = (const char*)xb + (size_t)stok[r] * (HH * 2) + sl * 16;
    } else if (c < 1536) {
      int cc = c - 1024, r = cc >> 3, sl = (cc & 7) ^ (r & 7);
      g = (const char*)gwt + ((size_t)e * II + nBase + r) * (HH * 2) + sl * 16;
    } else {
      int cc = c - 1536, r = cc >> 3, sl = (cc & 7) ^ (r & 7);
      g = (const char*)uwt + ((size_t)e * II + nBase + r) * (HH * 2) + sl * 16;
    }
    gaddr[j] = g;
  }

  int q = lane >> 4, m16 = lane & 15;
  int wr = wave & 1, wc = wave >> 1;
  int faddrA[4][2], faddrBg[2][2], faddrBu[2][2];
#pragma unroll
  for (int mi = 0; mi < 4; ++mi) {
    int R = wr * 64 + mi * 16 + m16;
#pragma unroll
    for (int h = 0; h < 2; ++h)
      faddrA[mi][h] = (R * 8 + ((h * 4 + q) ^ (R & 7))) * 16;
  }
#pragma unroll
  for (int ni = 0; ni < 2; ++ni) {
    int n = wc * 32 + ni * 16 + m16;
#pragma unroll
    for (int h = 0; h < 2; ++h) {
      faddrBg[ni][h] = (1024 + n * 8 + ((h * 4 + q) ^ (n & 7))) * 16;
      faddrBu[ni][h] = (1536 + n * 8 + ((h * 4 + q) ^ (n & 7))) * 16;
    }
  }

  f32x4 zero4 = {0.f, 0.f, 0.f, 0.f};
  f32x4 accG[4][2], accU[4][2];
#pragma unroll
  for (int mi = 0; mi < 4; ++mi)
#pragma unroll
    for (int ni = 0; ni < 2; ++ni) { accG[mi][ni] = zero4; accU[mi][ni] = zero4; }

  const char* smemc = (const char*)smem;
  for (int kt = 0; kt < HH / 64; ++kt) {
    __syncthreads();
#pragma unroll
    for (int j = 0; j < 8; ++j) {
      gl_lds16(gaddr[j], (char*)smem + (size_t)(wave * 512 + j * 64) * 16);
      gaddr[j] += 128;
    }
    __syncthreads();
#pragma unroll
    for (int h = 0; h < 2; ++h) {
      bf16x8 aF[4], bG[2], bU[2];
#pragma unroll
      for (int mi = 0; mi < 4; ++mi) aF[mi] = *(const bf16x8*)(smemc + faddrA[mi][h]);
#pragma unroll
      for (int ni = 0; ni < 2; ++ni) {
        bG[ni] = *(const bf16x8*)(smemc + faddrBg[ni][h]);
        bU[ni] = *(const bf16x8*)(smemc + faddrBu[ni][h]);
      }
#pragma unroll
      for (int mi = 0; mi < 4; ++mi)
#pragma unroll
        for (int ni = 0; ni < 2; ++ni) {
          accG[mi][ni] = __builtin_amdgcn_mfma_f32_16x16x32_bf16(aF[mi], bG[ni], accG[mi][ni], 0, 0, 0);
          accU[mi][ni] = __builtin_amdgcn_mfma_f32_16x16x32_bf16(aF[mi], bU[ni], accU[mi][ni], 0, 0, 0);
        }
    }
  }

  int hb = hb0 + mBase;
  int rowsValid = cn - mBase; if (rowsValid > 128) rowsValid = 128;
#pragma unroll
  for (int mi = 0; mi < 4; ++mi)
#pragma unroll
    for (int ni = 0; ni < 2; ++ni)
#pragma unroll
      for (int r = 0; r < 4; ++r) {
        int row = wr * 64 + mi * 16 + q * 4 + r;
        if (row < rowsValid) {
          float g = accG[mi][ni][r], u = accU[mi][ni][r];
          float h = g / (1.f + __expf(-g)) * u;
          hidden[(size_t)(hb + row) * II + nBase + wc * 32 + ni * 16 + m16] = f2bf(h);
        }
      }
}

// ---------------- GEMM2: hidden @ out_w -> expert_out fp32 ----------------
// 128(M) x 64(N), BK=64; LDS: A 1024 chunks, B 512 chunks (24KB) -> 1024 active blocks
__launch_bounds__(256, 3)
__global__ void gemm2_kernel(const unsigned short* __restrict__ hidden,
                             const unsigned short* __restrict__ owt,
                             float* __restrict__ expert_out,
                             const int* __restrict__ cnt) {
  int e = blockIdx.z;
  int cn = cnt[e * CSTRIDE];
  int hb0 = 0;
  for (int i = 0; i < EE; ++i) hb0 += (i < e) ? cnt[i * CSTRIDE] : 0;
  int mBase = blockIdx.y * 128;
  if (mBase >= cn) return;
  int nBase = blockIdx.x * 64;

  __shared__ __align__(16) unsigned short smem[12288];  // 1536 x 16B chunks

  int tid = threadIdx.x, wave = tid >> 6, lane = tid & 63;
  int hb = hb0 + mBase;
  const char* gaddr[6];
#pragma unroll
  for (int j = 0; j < 6; ++j) {
    int c = wave * 384 + j * 64 + lane;
    const char* g;
    if (c < 1024) {
      int r = c >> 3, sl = (c & 7) ^ (r & 7);
      g = (const char*)hidden + (size_t)(hb + r) * (II * 2) + sl * 16;
    } else {
      int cc = c - 1024, r = cc >> 3, sl = (cc & 7) ^ (r & 7);
      g = (const char*)owt + ((size_t)e * HH + nBase + r) * (II * 2) + sl * 16;
    }
    gaddr[j] = g;
  }

  int q = lane >> 4, m16 = lane & 15;
  int wr = wave & 1, wc = wave >> 1;
  int faddrA[4][2], faddrB[2][2];
#pragma unroll
  for (int mi = 0; mi < 4; ++mi) {
    int R = wr * 64 + mi * 16 + m16;
#pragma unroll
    for (int h = 0; h < 2; ++h)
      faddrA[mi][h] = (R * 8 + ((h * 4 + q) ^ (R & 7))) * 16;
  }
#pragma unroll
  for (int ni = 0; ni < 2; ++ni) {
    int n = wc * 32 + ni * 16 + m16;
#pragma unroll
    for (int h = 0; h < 2; ++h)
      faddrB[ni][h] = (1024 + n * 8 + ((h * 4 + q) ^ (n & 7))) * 16;
  }

  f32x4 zero4 = {0.f, 0.f, 0.f, 0.f};
  f32x4 acc[4][2];
#pragma unroll
  for (int mi = 0; mi < 4; ++mi)
#pragma unroll
    for (int ni = 0; ni < 2; ++ni) acc[mi][ni] = zero4;

  const char* smemc = (const char*)smem;
  for (int kt = 0; kt < II / 64; ++kt) {
    __syncthreads();
#pragma unroll
    for (int j = 0; j < 6; ++j) {
      gl_lds16(gaddr[j], (char*)smem + (size_t)(wave * 384 + j * 64) * 16);
      gaddr[j] += 128;
    }
    __syncthreads();
#pragma unroll
    for (int h = 0; h < 2; ++h) {
      bf16x8 aF[4], bF[2];
#pragma unroll
      for (int mi = 0; mi < 4; ++mi) aF[mi] = *(const bf16x8*)(smemc + faddrA[mi][h]);
#pragma unroll
      for (int ni = 0; ni < 2; ++ni) bF[ni] = *(const bf16x8*)(smemc + faddrB[ni][h]);
#pragma unroll
      for (int mi = 0; mi < 4; ++mi)
#pragma unroll
        for (int ni = 0; ni < 2; ++ni)
          acc[mi][ni] = __builtin_amdgcn_mfma_f32_16x16x32_bf16(aF[mi], bF[ni], acc[mi][ni], 0, 0, 0);
    }
  }

  int rowsValid = cn - mBase; if (rowsValid > 128) rowsValid = 128;
#pragma unroll
  for (int mi = 0; mi < 4; ++mi)
#pragma unroll
    for (int ni = 0; ni < 2; ++ni)
#pragma unroll
      for (int r = 0; r < 4; ++r) {
        int row = wr * 64 + mi * 16 + q * 4 + r;
        if (row < rowsValid)
          expert_out[(size_t)(hb + row) * HH + nBase + wc * 32 + ni * 16 + m16] = acc[mi][ni][r];
      }
}

// ---------------- combine: out[t] = w0*eo[row0] + w1*eo[row1] ----------------
__global__ void combine_kernel(const float* __restrict__ expert_out,
                               const int* __restrict__ cnt, const int* __restrict__ tslot,
                               const float2* __restrict__ tw, float* __restrict__ out) {
  int pre[EE];
  int s = 0;
#pragma unroll
  for (int e = 0; e < EE; ++e) { pre[e] = s; s += cnt[e * CSTRIDE]; }
  int t = blockIdx.x;
  int s0 = tslot[t * 2], s1 = tslot[t * 2 + 1];
  float2 w = tw[t];
  int r0 = pre[s0 >> 16] + (s0 & 0xFFFF);
  int r1 = pre[s1 >> 16] + (s1 & 0xFFFF);
  const float4* a = (const float4*)(expert_out + (size_t)r0 * HH);
  const float4* b = (const float4*)(expert_out + (size_t)r1 * HH);
  float4* o = (float4*)(out + (size_t)t * HH);
  int c = threadIdx.x;
  float4 av = a[c], bv = b[c];
  o[c] = make_float4(w.x * av.x + w.y * bv.x, w.x * av.y + w.y * bv.y,
                     w.x * av.z + w.y * bv.z, w.x * av.w + w.y * bv.w);
}

extern "C" void kernel_launch(void* const* d_in, const int* in_sizes, int n_in,
                              void* d_out, int out_size, void* d_ws, size_t ws_size,
                              hipStream_t stream) {
  (void)in_sizes; (void)n_in; (void)out_size; (void)ws_size;
  const float* x  = (const float*)d_in[0];
  const float* rw = (const float*)d_in[1];
  const float* gw = (const float*)d_in[2];
  const float* uw = (const float*)d_in[3];
  const float* ow = (const float*)d_in[4];
  float* out = (float*)d_out;                 // [T*H]
  float* logits = out + (size_t)TT * HH;      // [T*E]

  char* ws = (char*)d_ws;
  size_t o = 0;
  auto alloc = [&](size_t bytes) {
    char* p = ws + o;
    o += (bytes + 255) & ~(size_t)255;
    return p;
  };
  unsigned short* xb  = (unsigned short*)alloc((size_t)TT * HH * 2);
  unsigned short* gwt = (unsigned short*)alloc((size_t)EE * II * HH * 2);
  unsigned short* uwt = (unsigned short*)alloc((size_t)EE * II * HH * 2);
  unsigned short* owt = (unsigned short*)alloc((size_t)EE * HH * II * 2);
  unsigned short* hidden = (unsigned short*)alloc((size_t)(2 * TT + 128) * II * 2);
  int*   cnt   = (int*)alloc(EE * CSTRIDE * 4);
  int*   list  = (int*)alloc((size_t)EE * TT * 4);
  int*   tslot = (int*)alloc((size_t)TT * 2 * 4);
  float2* tw   = (float2*)alloc((size_t)TT * 8);
  // expert_out [2*TT+128][HH] fp32 aliases gwt+uwt (dead after gemm1): 34.1 MB <= 67 MB
  float* expert_out = (float*)gwt;

  hipMemsetAsync(cnt, 0, EE * CSTRIDE * 4, stream);

  prep_kernel<<<dim3(512, 1, 4 * EE), 256, 0, stream>>>(gw, uw, ow, x, gwt, uwt, owt, xb);
  router_kernel<<<TT / RB, 256, 0, stream>>>(x, rw, logits, cnt, list, tslot, tw);
  gemm1_kernel<<<dim3(II / 64, TT / 128, EE), 256, 0, stream>>>(xb, gwt, uwt, hidden, cnt, list);
  gemm2_kernel<<<dim3(HH / 64, TT / 128, EE), 256, 0, stream>>>(hidden, owt, expert_out, cnt);
  combine_kernel<<<TT, 256, 0, stream>>>(expert_out, cnt, tslot, tw, out);
}

// Round 6
// 403.133 us; speedup vs baseline: 1.1468x; 1.1468x over previous
//
#include <hip/hip_runtime.h>
#include <hip/hip_bf16.h>
#include <stdint.h>

#define TT 4096   // tokens = B*S
#define HH 1024   // hidden
#define II 2048   // intermediate
#define EE 8      // experts
#define RB 16     // router tokens per block
#define NRB (TT / RB)          // 256 router blocks
#define CSTRIDE 32             // cnt padding: one counter per 128-B line

typedef short bf16x8 __attribute__((ext_vector_type(8)));
typedef float f32x4 __attribute__((ext_vector_type(4)));

__device__ __forceinline__ unsigned short f2bf(float f) {
  unsigned u = __float_as_uint(f);
  u += 0x7FFF + ((u >> 16) & 1);   // RNE
  return (unsigned short)(u >> 16);
}

__device__ __forceinline__ void gl_lds16(const void* g, void* l) {
  auto gp = reinterpret_cast<const __attribute__((address_space(1))) unsigned int*>(
      reinterpret_cast<uintptr_t>(g));
  auto lp = reinterpret_cast<__attribute__((address_space(3))) unsigned int*>(
      reinterpret_cast<uintptr_t>(l));
  __builtin_amdgcn_global_load_lds(gp, lp, 16, 0, 0);
}

// ------- 64x64 transpose tile: [M][N] fp32 -> [N][M] bf16 -------
// tl: 2048 uints of LDS. Row n holds 32 dwords (m-pairs); phys dword = (j+n)&31.
__device__ __forceinline__ void transpose_tile(const float* __restrict__ in,
                                               unsigned short* __restrict__ out,
                                               int M, int N, int mB, int nB,
                                               unsigned int* tl, int tid) {
  union F4 { float4 v; float f[4]; };
  int c4 = (tid & 15) * 4;   // n base
  int mp = tid >> 4;         // 0..15
#pragma unroll
  for (int it = 0; it < 2; ++it) {
    int m = (mp + it * 16) * 2;
    const float* p0 = in + (size_t)(mB + m) * N + nB + c4;
    F4 a, b;
    a.v = *(const float4*)p0;
    b.v = *(const float4*)(p0 + N);
    int mdw = m >> 1;
#pragma unroll
    for (int i = 0; i < 4; ++i) {
      int n = c4 + i;
      unsigned v = (unsigned)f2bf(a.f[i]) | ((unsigned)f2bf(b.f[i]) << 16);
      tl[n * 32 + ((mdw + n) & 31)] = v;
    }
  }
  __syncthreads();
  int n2 = tid >> 3;          // 0..31
  int md8 = (tid & 7) * 4;    // dword base within row
#pragma unroll
  for (int it = 0; it < 2; ++it) {
    int n = n2 + it * 32;
    unsigned vv[4];
#pragma unroll
    for (int i = 0; i < 4; ++i)
      vv[i] = tl[n * 32 + ((md8 + i + n) & 31)];
    uint4 o4 = make_uint4(vv[0], vv[1], vv[2], vv[3]);
    *(uint4*)(out + (size_t)(nB + n) * M + mB + md8 * 2) = o4;
  }
}

// ------- front: router phase A (no global atomics, inline x-cast) + gate/up transpose -------
// blocks 0..255: router tokens b*16..+15 ; blocks 256..8447: gate/up 64x64 tiles
__global__ void front_kernel(const float* __restrict__ x, const float* __restrict__ rw,
                             const float* __restrict__ gw, const float* __restrict__ uw,
                             float* __restrict__ logits_out, unsigned short* __restrict__ xb,
                             unsigned short* __restrict__ gwt, unsigned short* __restrict__ uwt,
                             int* __restrict__ gcnt, int2* __restrict__ ttop) {
  __shared__ unsigned int tl[2048];
  int b = blockIdx.x;
  int tid = threadIdx.x;

  if (b >= NRB) {
    int idx = b - NRB;         // 0..8191
    int which = idx >> 12;     // 0 gate, 1 up
    int r = idx & 4095;
    int e = r >> 9;
    int tile = r & 511;        // N/64=32 x M/64=16
    int bx = tile & 31, by = tile >> 5;
    const float* in = (which ? uw : gw) + (size_t)e * HH * II;
    unsigned short* out = (which ? uwt : gwt) + (size_t)e * HH * II;
    transpose_tile(in, out, HH, II, by * 64, bx * 64, tl, tid);
    return;
  }

  __shared__ int bcnt[EE];
  int wave = tid >> 6, lane = tid & 63;
  if (tid < EE) bcnt[tid] = 0;
  __syncthreads();
  int t0 = b * RB;

  for (int sub = 0; sub < RB / 4; ++sub) {
    int li = sub * 4 + wave;
    int t = t0 + li;
    float acc[EE];
#pragma unroll
    for (int e = 0; e < EE; ++e) acc[e] = 0.f;
#pragma unroll
    for (int j = 0; j < 4; ++j) {
      int h = j * 256 + lane * 4;
      union F4 { float4 v; float f[4]; } xv;
      xv.v = *(const float4*)(x + (size_t)t * HH + h);
      union { unsigned short s[4]; uint2 v; } pk;
#pragma unroll
      for (int i = 0; i < 4; ++i) pk.s[i] = f2bf(xv.f[i]);
      *(uint2*)(xb + (size_t)t * HH + h) = pk.v;
#pragma unroll
      for (int i = 0; i < 4; ++i) {
        const float4* r4 = (const float4*)(rw + (h + i) * EE);
        float4 r0 = r4[0], r1 = r4[1];
        float xs = xv.f[i];
        acc[0] += xs * r0.x; acc[1] += xs * r0.y; acc[2] += xs * r0.z; acc[3] += xs * r0.w;
        acc[4] += xs * r1.x; acc[5] += xs * r1.y; acc[6] += xs * r1.z; acc[7] += xs * r1.w;
      }
    }
#pragma unroll
    for (int e = 0; e < EE; ++e)
#pragma unroll
      for (int off = 32; off; off >>= 1) acc[e] += __shfl_down(acc[e], off);
    if (lane == 0) {
      float4* lo = (float4*)(logits_out + (size_t)t * EE);
      lo[0] = make_float4(acc[0], acc[1], acc[2], acc[3]);
      lo[1] = make_float4(acc[4], acc[5], acc[6], acc[7]);
      int e0 = 0; float b0 = acc[0];
#pragma unroll
      for (int e = 1; e < EE; ++e) if (acc[e] > b0) { b0 = acc[e]; e0 = e; }
      int e1 = -1; float b1 = -3.4e38f;
#pragma unroll
      for (int e = 0; e < EE; ++e) if (e != e0 && acc[e] > b1) { b1 = acc[e]; e1 = e; }
      float w0 = 1.f / (1.f + __expf(b1 - b0));
      int lp0 = atomicAdd(&bcnt[e0], 1);   // LDS atomic, intra-block only
      int lp1 = atomicAdd(&bcnt[e1], 1);
      ttop[t] = make_int2(e0 | (e1 << 3) | (lp0 << 6) | (lp1 << 11), __float_as_int(w0));
    }
  }
  __syncthreads();
  if (tid < EE) gcnt[b * EE + tid] = bcnt[tid];
}

// ------- scatter: deterministic token placement (redundant prefix per block) -------
__global__ void scatter_kernel(const int* __restrict__ gcnt, const int2* __restrict__ ttop,
                               int* __restrict__ cnt, int* __restrict__ list,
                               int* __restrict__ tslot, float2* __restrict__ tw) {
  __shared__ int raw[NRB * EE];
  __shared__ int base[NRB][EE];
  int tid = threadIdx.x;
  for (int i = tid; i < NRB * EE; i += 256) raw[i] = gcnt[i];
  __syncthreads();
  if (tid < EE) {
    int s = 0;
    for (int b = 0; b < NRB; ++b) { base[b][tid] = s; s += raw[b * EE + tid]; }
    if (blockIdx.x == 0) cnt[tid * CSTRIDE] = s;
  }
  __syncthreads();
  int t = blockIdx.x * 256 + tid;
  int2 ti = ttop[t];
  int v = ti.x;
  float w0 = __int_as_float(ti.y);
  int e0 = v & 7, e1 = (v >> 3) & 7, lp0 = (v >> 6) & 31, lp1 = (v >> 11) & 31;
  int b = t >> 4;
  int p0 = base[b][e0] + lp0;
  int p1 = base[b][e1] + lp1;
  list[e0 * TT + p0] = t;
  list[e1 * TT + p1] = t;
  tslot[t * 2]     = (e0 << 16) | p0;
  tslot[t * 2 + 1] = (e1 << 16) | p1;
  tw[t] = make_float2(w0, 1.f - w0);
}

// ---------------- GEMM1 (+ fused out_w transpose blocks at blockIdx.y >= 32) ----------------
// gemm: 128(M) x 64(N) x2 tensors, BK=64; LDS: A 1024 chunks, Bg 512, Bu 512 (32KB)
__launch_bounds__(256, 3)
__global__ void gemm1_kernel(const unsigned short* __restrict__ xb,
                             const unsigned short* __restrict__ gwt,
                             const unsigned short* __restrict__ uwt,
                             const float* __restrict__ ow, unsigned short* __restrict__ owt,
                             unsigned short* __restrict__ hidden,
                             const int* __restrict__ cnt, const int* __restrict__ list) {
  __shared__ __align__(16) unsigned short smem[16384];  // 2048 x 16B chunks
  __shared__ int stok[128];
  int tid = threadIdx.x;
  int e = blockIdx.z;

  if (blockIdx.y >= 32) {
    // out_w transpose: [II][HH] -> [HH][II] for expert e
    int tile = (blockIdx.y - 32) * 32 + blockIdx.x;  // 0..511
    int bx = tile & 15, by = tile >> 4;              // N/64=16, M/64=32
    transpose_tile(ow + (size_t)e * II * HH, owt + (size_t)e * II * HH,
                   II, HH, by * 64, bx * 64, (unsigned int*)smem, tid);
    return;
  }

  int cn = cnt[e * CSTRIDE];
  int hb0 = 0;
  for (int i = 0; i < EE; ++i) hb0 += (i < e) ? cnt[i * CSTRIDE] : 0;
  int mBase = blockIdx.y * 128;
  if (mBase >= cn) return;
  int nBase = blockIdx.x * 64;

  int wave = tid >> 6, lane = tid & 63;
  if (tid < 128) {
    int g = mBase + tid;
    stok[tid] = list[e * TT + (g < cn ? g : cn - 1)];
  }
  __syncthreads();

  const char* gaddr[8];
#pragma unroll
  for (int j = 0; j < 8; ++j) {
    int c = wave * 512 + j * 64 + lane;
    const char* g;
    if (c < 1024) {
      int r = c >> 3, sl = (c & 7) ^ (r & 7);
      g = (const char*)xb + (size_t)stok[r] * (HH * 2) + sl * 16;
    } else if (c < 1536) {
      int cc = c - 1024, r = cc >> 3, sl = (cc & 7) ^ (r & 7);
      g = (const char*)gwt + ((size_t)e * II + nBase + r) * (HH * 2) + sl * 16;
    } else {
      int cc = c - 1536, r = cc >> 3, sl = (cc & 7) ^ (r & 7);
      g = (const char*)uwt + ((size_t)e * II + nBase + r) * (HH * 2) + sl * 16;
    }
    gaddr[j] = g;
  }

  int q = lane >> 4, m16 = lane & 15;
  int wr = wave & 1, wc = wave >> 1;
  int faddrA[4][2], faddrBg[2][2], faddrBu[2][2];
#pragma unroll
  for (int mi = 0; mi < 4; ++mi) {
    int R = wr * 64 + mi * 16 + m16;
#pragma unroll
    for (int h = 0; h < 2; ++h)
      faddrA[mi][h] = (R * 8 + ((h * 4 + q) ^ (R & 7))) * 16;
  }
#pragma unroll
  for (int ni = 0; ni < 2; ++ni) {
    int n = wc * 32 + ni * 16 + m16;
#pragma unroll
    for (int h = 0; h < 2; ++h) {
      faddrBg[ni][h] = (1024 + n * 8 + ((h * 4 + q) ^ (n & 7))) * 16;
      faddrBu[ni][h] = (1536 + n * 8 + ((h * 4 + q) ^ (n & 7))) * 16;
    }
  }

  f32x4 zero4 = {0.f, 0.f, 0.f, 0.f};
  f32x4 accG[4][2], accU[4][2];
#pragma unroll
  for (int mi = 0; mi < 4; ++mi)
#pragma unroll
    for (int ni = 0; ni < 2; ++ni) { accG[mi][ni] = zero4; accU[mi][ni] = zero4; }

  const char* smemc = (const char*)smem;
  for (int kt = 0; kt < HH / 64; ++kt) {
    __syncthreads();
#pragma unroll
    for (int j = 0; j < 8; ++j) {
      gl_lds16(gaddr[j], (char*)smem + (size_t)(wave * 512 + j * 64) * 16);
      gaddr[j] += 128;
    }
    __syncthreads();
#pragma unroll
    for (int h = 0; h < 2; ++h) {
      bf16x8 aF[4], bG[2], bU[2];
#pragma unroll
      for (int mi = 0; mi < 4; ++mi) aF[mi] = *(const bf16x8*)(smemc + faddrA[mi][h]);
#pragma unroll
      for (int ni = 0; ni < 2; ++ni) {
        bG[ni] = *(const bf16x8*)(smemc + faddrBg[ni][h]);
        bU[ni] = *(const bf16x8*)(smemc + faddrBu[ni][h]);
      }
#pragma unroll
      for (int mi = 0; mi < 4; ++mi)
#pragma unroll
        for (int ni = 0; ni < 2; ++ni) {
          accG[mi][ni] = __builtin_amdgcn_mfma_f32_16x16x32_bf16(aF[mi], bG[ni], accG[mi][ni], 0, 0, 0);
          accU[mi][ni] = __builtin_amdgcn_mfma_f32_16x16x32_bf16(aF[mi], bU[ni], accU[mi][ni], 0, 0, 0);
        }
    }
  }

  int hb = hb0 + mBase;
  int rowsValid = cn - mBase; if (rowsValid > 128) rowsValid = 128;
#pragma unroll
  for (int mi = 0; mi < 4; ++mi)
#pragma unroll
    for (int ni = 0; ni < 2; ++ni)
#pragma unroll
      for (int r = 0; r < 4; ++r) {
        int row = wr * 64 + mi * 16 + q * 4 + r;
        if (row < rowsValid) {
          float g = accG[mi][ni][r], u = accU[mi][ni][r];
          float h = g / (1.f + __expf(-g)) * u;
          hidden[(size_t)(hb + row) * II + nBase + wc * 32 + ni * 16 + m16] = f2bf(h);
        }
      }
}

// ---------------- GEMM2: hidden @ out_w -> expert_out fp32 ----------------
// 128(M) x 64(N), BK=64; LDS: A 1024 chunks, B 512 chunks (24KB)
__launch_bounds__(256, 3)
__global__ void gemm2_kernel(const unsigned short* __restrict__ hidden,
                             const unsigned short* __restrict__ owt,
                             float* __restrict__ expert_out,
                             const int* __restrict__ cnt) {
  int e = blockIdx.z;
  int cn = cnt[e * CSTRIDE];
  int hb0 = 0;
  for (int i = 0; i < EE; ++i) hb0 += (i < e) ? cnt[i * CSTRIDE] : 0;
  int mBase = blockIdx.y * 128;
  if (mBase >= cn) return;
  int nBase = blockIdx.x * 64;

  __shared__ __align__(16) unsigned short smem[12288];  // 1536 x 16B chunks

  int tid = threadIdx.x, wave = tid >> 6, lane = tid & 63;
  int hb = hb0 + mBase;
  const char* gaddr[6];
#pragma unroll
  for (int j = 0; j < 6; ++j) {
    int c = wave * 384 + j * 64 + lane;
    const char* g;
    if (c < 1024) {
      int r = c >> 3, sl = (c & 7) ^ (r & 7);
      g = (const char*)hidden + (size_t)(hb + r) * (II * 2) + sl * 16;
    } else {
      int cc = c - 1024, r = cc >> 3, sl = (cc & 7) ^ (r & 7);
      g = (const char*)owt + ((size_t)e * HH + nBase + r) * (II * 2) + sl * 16;
    }
    gaddr[j] = g;
  }

  int q = lane >> 4, m16 = lane & 15;
  int wr = wave & 1, wc = wave >> 1;
  int faddrA[4][2], faddrB[2][2];
#pragma unroll
  for (int mi = 0; mi < 4; ++mi) {
    int R = wr * 64 + mi * 16 + m16;
#pragma unroll
    for (int h = 0; h < 2; ++h)
      faddrA[mi][h] = (R * 8 + ((h * 4 + q) ^ (R & 7))) * 16;
  }
#pragma unroll
  for (int ni = 0; ni < 2; ++ni) {
    int n = wc * 32 + ni * 16 + m16;
#pragma unroll
    for (int h = 0; h < 2; ++h)
      faddrB[ni][h] = (1024 + n * 8 + ((h * 4 + q) ^ (n & 7))) * 16;
  }

  f32x4 zero4 = {0.f, 0.f, 0.f, 0.f};
  f32x4 acc[4][2];
#pragma unroll
  for (int mi = 0; mi < 4; ++mi)
#pragma unroll
    for (int ni = 0; ni < 2; ++ni) acc[mi][ni] = zero4;

  const char* smemc = (const char*)smem;
  for (int kt = 0; kt < II / 64; ++kt) {
    __syncthreads();
#pragma unroll
    for (int j = 0; j < 6; ++j) {
      gl_lds16(gaddr[j], (char*)smem + (size_t)(wave * 384 + j * 64) * 16);
      gaddr[j] += 128;
    }
    __syncthreads();
#pragma unroll
    for (int h = 0; h < 2; ++h) {
      bf16x8 aF[4], bF[2];
#pragma unroll
      for (int mi = 0; mi < 4; ++mi) aF[mi] = *(const bf16x8*)(smemc + faddrA[mi][h]);
#pragma unroll
      for (int ni = 0; ni < 2; ++ni) bF[ni] = *(const bf16x8*)(smemc + faddrB[ni][h]);
#pragma unroll
      for (int mi = 0; mi < 4; ++mi)
#pragma unroll
        for (int ni = 0; ni < 2; ++ni)
          acc[mi][ni] = __builtin_amdgcn_mfma_f32_16x16x32_bf16(aF[mi], bF[ni], acc[mi][ni], 0, 0, 0);
    }
  }

  int rowsValid = cn - mBase; if (rowsValid > 128) rowsValid = 128;
#pragma unroll
  for (int mi = 0; mi < 4; ++mi)
#pragma unroll
    for (int ni = 0; ni < 2; ++ni)
#pragma unroll
      for (int r = 0; r < 4; ++r) {
        int row = wr * 64 + mi * 16 + q * 4 + r;
        if (row < rowsValid)
          expert_out[(size_t)(hb + row) * HH + nBase + wc * 32 + ni * 16 + m16] = acc[mi][ni][r];
      }
}

// ---------------- combine: out[t] = w0*eo[row0] + w1*eo[row1] ----------------
__global__ void combine_kernel(const float* __restrict__ expert_out,
                               const int* __restrict__ cnt, const int* __restrict__ tslot,
                               const float2* __restrict__ tw, float* __restrict__ out) {
  int pre[EE];
  int s = 0;
#pragma unroll
  for (int e = 0; e < EE; ++e) { pre[e] = s; s += cnt[e * CSTRIDE]; }
  int t = blockIdx.x;
  int s0 = tslot[t * 2], s1 = tslot[t * 2 + 1];
  float2 w = tw[t];
  int r0 = pre[s0 >> 16] + (s0 & 0xFFFF);
  int r1 = pre[s1 >> 16] + (s1 & 0xFFFF);
  const float4* a = (const float4*)(expert_out + (size_t)r0 * HH);
  const float4* b = (const float4*)(expert_out + (size_t)r1 * HH);
  float4* o = (float4*)(out + (size_t)t * HH);
  int c = threadIdx.x;
  float4 av = a[c], bv = b[c];
  o[c] = make_float4(w.x * av.x + w.y * bv.x, w.x * av.y + w.y * bv.y,
                     w.x * av.z + w.y * bv.z, w.x * av.w + w.y * bv.w);
}

extern "C" void kernel_launch(void* const* d_in, const int* in_sizes, int n_in,
                              void* d_out, int out_size, void* d_ws, size_t ws_size,
                              hipStream_t stream) {
  (void)in_sizes; (void)n_in; (void)out_size; (void)ws_size;
  const float* x  = (const float*)d_in[0];
  const float* rw = (const float*)d_in[1];
  const float* gw = (const float*)d_in[2];
  const float* uw = (const float*)d_in[3];
  const float* ow = (const float*)d_in[4];
  float* out = (float*)d_out;                 // [T*H]
  float* logits = out + (size_t)TT * HH;      // [T*E]

  char* ws = (char*)d_ws;
  size_t o = 0;
  auto alloc = [&](size_t bytes) {
    char* p = ws + o;
    o += (bytes + 255) & ~(size_t)255;
    return p;
  };
  unsigned short* xb  = (unsigned short*)alloc((size_t)TT * HH * 2);
  unsigned short* gwt = (unsigned short*)alloc((size_t)EE * II * HH * 2);
  unsigned short* uwt = (unsigned short*)alloc((size_t)EE * II * HH * 2);
  unsigned short* owt = (unsigned short*)alloc((size_t)EE * HH * II * 2);
  unsigned short* hidden = (unsigned short*)alloc((size_t)(2 * TT + 128) * II * 2);
  int*    cnt   = (int*)alloc(EE * CSTRIDE * 4);
  int*    list  = (int*)alloc((size_t)EE * TT * 4);
  int*    tslot = (int*)alloc((size_t)TT * 2 * 4);
  float2* tw    = (float2*)alloc((size_t)TT * 8);
  int*    gcnt  = (int*)alloc((size_t)NRB * EE * 4);
  int2*   ttop  = (int2*)alloc((size_t)TT * 8);
  // expert_out [2*TT+128][HH] fp32 aliases gwt+uwt (dead after gemm1): 34.1 MB <= 67 MB
  float* expert_out = (float*)gwt;

  front_kernel<<<NRB + 8192, 256, 0, stream>>>(x, rw, gw, uw, logits, xb, gwt, uwt, gcnt, ttop);
  scatter_kernel<<<TT / 256, 256, 0, stream>>>(gcnt, ttop, cnt, list, tslot, tw);
  gemm1_kernel<<<dim3(32, 48, EE), 256, 0, stream>>>(xb, gwt, uwt, ow, owt, hidden, cnt, list);
  gemm2_kernel<<<dim3(HH / 64, TT / 128, EE), 256, 0, stream>>>(hidden, owt, expert_out, cnt);
  combine_kernel<<<TT, 256, 0, stream>>>(expert_out, cnt, tslot, tw, out);
}